// Round 1
// baseline (205.375 us; speedup 1.0000x reference)
//
#include <hip/hip_runtime.h>

// APMLSparse: B=4, N=M=4096, D=3.
// loss = sum_rows sum_{kept j} p_ij * d_ij, p = softmax_j(-d_i),
// kept = descending-p prefix until cumulative mass >= P_MIN = 0.8.
//
// R8: latency-bound fix (real VALU busy ~27%; 3.6 waves/SIMD; serial probe
// rounds dominate wave span). Changes vs R7:
//  - Phase A: ONE 4-threshold exact pass (warm bracket +/- margin), 4
//    independent accumulator chains + interleaved 4-way DPP reduction,
//    replacing ~4 serial full scans. Classic single-threshold refine kept
//    only as a rare fallback.
//  - Warm start samples 512 elems (p[0..7], 2 chains), 6 probes.
//  - Band capacity 256 -> 512 (8 compact regs); cv[] eliminated (invalid
//    slots hold 0.0, all thresholds > 0).
//  - C1: two thresholds per round (interp + bisect), 2 interleaved chains.
//  - Setup: pmax/dppMax dropped; upper bound pTop = 1.0f (p = exp(-d) < 1).
//  - Value-critical paths bit-preserved: zl order, spd order, per-threshold
//    mass = serial-k cndmask-add chain + dppSum (same association as R7),
//    Phase D / tie logic untouched.

#define MCOLS 4096
#define KPT   64            // 4096 / 64 lanes
#define WPB   4             // waves per block
#define P_MIN 0.8f
#define CAP   512           // compact-band capacity (8 regs/lane)

// ---- DPP wave64 reductions (old=0 => disabled/out-of-range lanes add 0) ----
template <int CTRL, int RM, int BM, bool BC>
__device__ __forceinline__ float dpp_mov0(float x) {
    return __int_as_float(__builtin_amdgcn_update_dpp(
        0, __float_as_int(x), CTRL, RM, BM, BC));
}
__device__ __forceinline__ float dppSum(float v) {
    v += dpp_mov0<0x111, 0xF, 0xF, true >(v);   // row_shr:1
    v += dpp_mov0<0x112, 0xF, 0xF, true >(v);   // row_shr:2
    v += dpp_mov0<0x114, 0xF, 0xF, true >(v);   // row_shr:4
    v += dpp_mov0<0x118, 0xF, 0xF, true >(v);   // row_shr:8
    v += dpp_mov0<0x142, 0xA, 0xF, false>(v);   // row_bcast15 -> rows 1,3
    v += dpp_mov0<0x143, 0xC, 0xF, false>(v);   // row_bcast31 -> rows 2,3
    return __int_as_float(__builtin_amdgcn_readlane(__float_as_int(v), 63));
}
__device__ __forceinline__ void dppSum2(float& a, float& b) {
    a += dpp_mov0<0x111, 0xF, 0xF, true >(a); b += dpp_mov0<0x111, 0xF, 0xF, true >(b);
    a += dpp_mov0<0x112, 0xF, 0xF, true >(a); b += dpp_mov0<0x112, 0xF, 0xF, true >(b);
    a += dpp_mov0<0x114, 0xF, 0xF, true >(a); b += dpp_mov0<0x114, 0xF, 0xF, true >(b);
    a += dpp_mov0<0x118, 0xF, 0xF, true >(a); b += dpp_mov0<0x118, 0xF, 0xF, true >(b);
    a += dpp_mov0<0x142, 0xA, 0xF, false>(a); b += dpp_mov0<0x142, 0xA, 0xF, false>(b);
    a += dpp_mov0<0x143, 0xC, 0xF, false>(a); b += dpp_mov0<0x143, 0xC, 0xF, false>(b);
    a = __int_as_float(__builtin_amdgcn_readlane(__float_as_int(a), 63));
    b = __int_as_float(__builtin_amdgcn_readlane(__float_as_int(b), 63));
}
__device__ __forceinline__ void dppSum4(float& a, float& b, float& c, float& d) {
    a += dpp_mov0<0x111, 0xF, 0xF, true >(a); b += dpp_mov0<0x111, 0xF, 0xF, true >(b);
    c += dpp_mov0<0x111, 0xF, 0xF, true >(c); d += dpp_mov0<0x111, 0xF, 0xF, true >(d);
    a += dpp_mov0<0x112, 0xF, 0xF, true >(a); b += dpp_mov0<0x112, 0xF, 0xF, true >(b);
    c += dpp_mov0<0x112, 0xF, 0xF, true >(c); d += dpp_mov0<0x112, 0xF, 0xF, true >(d);
    a += dpp_mov0<0x114, 0xF, 0xF, true >(a); b += dpp_mov0<0x114, 0xF, 0xF, true >(b);
    c += dpp_mov0<0x114, 0xF, 0xF, true >(c); d += dpp_mov0<0x114, 0xF, 0xF, true >(d);
    a += dpp_mov0<0x118, 0xF, 0xF, true >(a); b += dpp_mov0<0x118, 0xF, 0xF, true >(b);
    c += dpp_mov0<0x118, 0xF, 0xF, true >(c); d += dpp_mov0<0x118, 0xF, 0xF, true >(d);
    a += dpp_mov0<0x142, 0xA, 0xF, false>(a); b += dpp_mov0<0x142, 0xA, 0xF, false>(b);
    c += dpp_mov0<0x142, 0xA, 0xF, false>(c); d += dpp_mov0<0x142, 0xA, 0xF, false>(d);
    a += dpp_mov0<0x143, 0xC, 0xF, false>(a); b += dpp_mov0<0x143, 0xC, 0xF, false>(b);
    c += dpp_mov0<0x143, 0xC, 0xF, false>(c); d += dpp_mov0<0x143, 0xC, 0xF, false>(d);
    a = __int_as_float(__builtin_amdgcn_readlane(__float_as_int(a), 63));
    b = __int_as_float(__builtin_amdgcn_readlane(__float_as_int(b), 63));
    c = __int_as_float(__builtin_amdgcn_readlane(__float_as_int(c), 63));
    d = __int_as_float(__builtin_amdgcn_readlane(__float_as_int(d), 63));
}
__device__ __forceinline__ float dppMax(float v) {   // nonneg inputs only
    v = fmaxf(v, dpp_mov0<0x111, 0xF, 0xF, true >(v));
    v = fmaxf(v, dpp_mov0<0x112, 0xF, 0xF, true >(v));
    v = fmaxf(v, dpp_mov0<0x114, 0xF, 0xF, true >(v));
    v = fmaxf(v, dpp_mov0<0x118, 0xF, 0xF, true >(v));
    v = fmaxf(v, dpp_mov0<0x142, 0xA, 0xF, false>(v));
    v = fmaxf(v, dpp_mov0<0x143, 0xC, 0xF, false>(v));
    return __int_as_float(__builtin_amdgcn_readlane(__float_as_int(v), 63));
}

__global__ __launch_bounds__(WPB * 64) void apml_row_wave(
        const float* __restrict__ x, const float* __restrict__ y,
        float* __restrict__ out) {
    __shared__ __align__(16) float scomp[WPB * CAP];
    __shared__ float wacc[WPB];

    const int tid  = threadIdx.x;
    const int wid  = tid >> 6;
    const int lane = tid & 63;
    const int row  = blockIdx.x * WPB + wid;
    const int b    = row >> 12;                 // row / 4096

    const float x0 = x[row * 3 + 0];
    const float x1 = x[row * 3 + 1];
    const float x2 = x[row * 3 + 2];
    const float* yb = y + (size_t)b * MCOLS * 3;

    // ---- setup: p = exp(-d), register-resident; Z via DPP (zl order kept) ----
    float p[KPT];
    float zl = 0.0f;
    #pragma unroll
    for (int k = 0; k < KPT; ++k) {
        const int j = k * 64 + lane;
        const float y0 = yb[j * 3 + 0];
        const float y1 = yb[j * 3 + 1];
        const float y2 = yb[j * 3 + 2];
        const float dx = x0 - y0, dy = x1 - y1, dz = x2 - y2;
        const float sq = fmaxf(dx * dx + dy * dy + dz * dz, 1e-12f); // EPS^2
        const float pk = __expf(-sqrtf(sq));
        p[k] = pk;
        zl  += pk;
    }
    const float Z      = dppSum(zl);
    const float target = P_MIN * Z;
    const float pTop   = 1.0f;   // p = exp(-d), d >= 1e-6 => p < 1.0f strictly

    // ---- sampled warm-start: 6 probes on p[0..7] (512 samples, 2 chains) ----
    float ssl = 0.0f, ssh = pTop;
    {
        float ea = 0.0f, eb = 0.0f;
        #pragma unroll
        for (int q = 0; q < 8; q += 2) { ea += p[q]; eb += p[q + 1]; }
        float eGl = 8.0f * dppSum(ea + eb);      // Ghat(0), scale 4096/512
        float eGh = 0.0f;
        for (int it = 0; it < 6; ++it) {
            float s;
            if (it & 1) {
                s = 0.5f * (ssl + ssh);
            } else {
                const float den = fmaxf(eGl - eGh, 1e-30f);
                s = ssl + (ssh - ssl) * ((eGl - target) / den);
            }
            if (!(s > ssl && s < ssh)) s = 0.5f * (ssl + ssh);
            if (!(s > ssl && s < ssh)) break;
            float ma = 0.0f, mb2 = 0.0f;
            #pragma unroll
            for (int q = 0; q < 8; q += 2) {
                ma  += (p[q]     >= s) ? p[q]     : 0.0f;
                mb2 += (p[q + 1] >= s) ? p[q + 1] : 0.0f;
            }
            const float m = 8.0f * dppSum(ma + mb2);
            if (m >= target) { ssl = s; eGl = m; }
            else             { ssh = s; eGh = m; }
        }
    }

    // ---- Phase A': ONE exact 4-threshold pass (warm bracket +/- margin) ----
    // Invariant produced: G(sl) >= target > G(sh), G(s) = mass of {p >= s}.
    const float wdu = ssh - ssl;
    const float u1  = fmaxf(ssl, 1e-30f);
    const float u0  = fmaxf(ssl - wdu, 0.5f * u1);
    const float u2  = ssh;
    const float u3  = fminf(ssh + wdu, pTop);

    float m0 = 0.0f, m1 = 0.0f, m2 = 0.0f, m3 = 0.0f;
    int   c0 = 0,    c1 = 0,    c2 = 0,    c3 = 0;
    #pragma unroll
    for (int k = 0; k < KPT; ++k) {
        const float pk = p[k];
        const bool g0 = (pk >= u0), g1 = (pk >= u1);
        const bool g2 = (pk >= u2), g3 = (pk >= u3);
        m0 += g0 ? pk : 0.0f; c0 += (int)__popcll(__ballot(g0));
        m1 += g1 ? pk : 0.0f; c1 += (int)__popcll(__ballot(g1));
        m2 += g2 ? pk : 0.0f; c2 += (int)__popcll(__ballot(g2));
        m3 += g3 ? pk : 0.0f; c3 += (int)__popcll(__ballot(g3));
    }
    dppSum4(m0, m1, m2, m3);

    float sl, sh, Gl, Gh;
    int   Cl, Ch;
    if      (m3 >= target) { sl = u3;   Gl = m3; Cl = c3;    sh = pTop; Gh = 0.0f; Ch = 0;  }
    else if (m2 >= target) { sl = u2;   Gl = m2; Cl = c2;    sh = u3;   Gh = m3;   Ch = c3; }
    else if (m1 >= target) { sl = u1;   Gl = m1; Cl = c1;    sh = u2;   Gh = m2;   Ch = c2; }
    else if (m0 >= target) { sl = u0;   Gl = m0; Cl = c0;    sh = u1;   Gh = m1;   Ch = c1; }
    else                   { sl = 0.0f; Gl = Z;  Cl = MCOLS; sh = u0;   Gh = m0;   Ch = c0; }

    // ---- rare fallback: classic single-threshold refine until band <= CAP ----
    for (int it = 0; it < 8 && (Cl - Ch) > CAP; ++it) {
        float s;
        if (it & 1) {
            s = 0.5f * (sl + sh);
        } else {
            const float den = fmaxf(Gl - Gh, 1e-30f);
            s = sl + (sh - sl) * ((Gl - target) / den);
        }
        if (!(s > sl && s < sh)) s = 0.5f * (sl + sh);
        if (!(s > sl && s < sh)) break;        // ulp-width bracket

        float m = 0.0f;
        int   c = 0;
        #pragma unroll
        for (int k = 0; k < KPT; ++k) {
            const bool ge = (p[k] >= s);
            m += ge ? p[k] : 0.0f;
            c += (int)__popcll(__ballot(ge));
        }
        m = dppSum(m);
        if (m >= target) { sl = s; Gl = m; Cl = c; }
        else             { sh = s; Gh = m; Ch = c; }
    }

    // ---- Phase B: compact band [sl, sh) into 8 regs per lane ----
    int Cb = 0;
    #pragma unroll
    for (int k = 0; k < KPT; ++k) {
        const bool band = (p[k] >= sl) && (p[k] < sh);
        const unsigned long long mk = __ballot(band);
        if (band) {
            const unsigned mlo = (unsigned)mk, mhi = (unsigned)(mk >> 32);
            const int within = __builtin_amdgcn_mbcnt_hi(
                                   mhi, __builtin_amdgcn_mbcnt_lo(mlo, 0));
            const int pos = Cb + within;
            if (pos < CAP) scomp[wid * CAP + pos] = p[k];
        }
        Cb += (int)__popcll(mk);
    }
    __builtin_amdgcn_s_waitcnt(0);             // drain ds_writes (same wave)
    const int Cc = (Cb < CAP) ? Cb : CAP;
    float cp[8];                                // invalid slots hold 0.0f
    #pragma unroll
    for (int q = 0; q < 8; ++q) {
        const int idx = q * 64 + lane;
        cp[q] = (idx < Cc) ? scomp[wid * CAP + idx] : 0.0f;
    }

    float pstar, mbv = 0.0f;
    int   cnt = 1;
    bool  haveTie;

    if (Cb > CAP) {
        // fallback (rare): keep everything >= sl (off by boundary elems)
        pstar = (sl > 0.0f) ? __uint_as_float(__float_as_uint(sl) - 1u) : 0.0f;
        haveTie = false;
    } else {
        // ---- Phase C1: fine probes, 2 thresholds per round (interp+bisect) ----
        float lo_s = sl, hi_s = sh, lo_G = Gl, hi_G = Gh;
        int   lo_C = Cl, hi_C = Ch;
        for (int it = 0; it < 6 && (lo_C - hi_C) > 2; ++it) {
            const float sB = 0.5f * (lo_s + hi_s);
            if (!(sB > lo_s && sB < hi_s)) break;   // ulp-width bracket
            float sA = lo_s + (hi_s - lo_s) *
                       ((lo_G - target) / fmaxf(lo_G - hi_G, 1e-30f));
            if (!(sA > lo_s && sA < hi_s)) sA = sB;
            const float t0 = fminf(sA, sB), t1 = fmaxf(sA, sB); // t0 <= t1, both > 0

            float a0 = 0.0f, a1 = 0.0f;
            int   k0 = 0,    k1 = 0;
            #pragma unroll
            for (int q = 0; q < 8; ++q) {
                const bool g0 = (cp[q] >= t0);      // invalid cp==0 excluded (t0>0)
                const bool g1 = (cp[q] >= t1);
                a0 += g0 ? cp[q] : 0.0f; k0 += (int)__popcll(__ballot(g0));
                a1 += g1 ? cp[q] : 0.0f; k1 += (int)__popcll(__ballot(g1));
            }
            dppSum2(a0, a1);
            const float M0 = Gh + a0, M1 = Gh + a1;    // M0 >= M1
            const int   D0 = Ch + k0, D1 = Ch + k1;
            if      (M1 >= target) { lo_s = t1; lo_G = M1; lo_C = D1; }
            else if (M0 >= target) { lo_s = t0; lo_G = M0; lo_C = D0;
                                     hi_s = t1; hi_G = M1; hi_C = D1; }
            else                   { hi_s = t0; hi_G = M0; hi_C = D0; }
        }

        // ---- Phase C2: exact distinct-value walk downward from hi_s ----
        float scur = hi_s, M = hi_G;
        bool ok = false;
        pstar = lo_s;
        for (int e = 0; e < 16; ++e) {
            float v0 = 0.0f, v1 = 0.0f;
            #pragma unroll
            for (int q = 0; q < 8; q += 2) {
                v0 = fmaxf(v0, (cp[q]     < scur) ? cp[q]     : 0.0f);
                v1 = fmaxf(v1, (cp[q + 1] < scur) ? cp[q + 1] : 0.0f);
            }
            const float v = dppMax(fmaxf(v0, v1));
            if (!(v > 0.0f)) break;            // fp knife-edge; fallback
            int cvn = 0;
            #pragma unroll
            for (int q = 0; q < 8; ++q)
                cvn += (int)__popcll(__ballot(cp[q] == v));   // v > 0 excludes invalid
            const float Mn = M + v * (float)cvn;  // exact: ties bit-identical
            if (Mn >= target) { pstar = v; mbv = M; cnt = cvn; ok = true; break; }
            M = Mn; scur = v;
        }
        haveTie = ok;
        if (!ok) {
            pstar = (lo_s > 0.0f) ? __uint_as_float(__float_as_uint(lo_s) - 1u)
                                  : 0.0f;
        }
    }

    // ---- Phase D: spd = sum_{p > p*} p * (-log p) via select-to-1 ----
    // (bit-identical to R7: same order, same select trick)
    float spd = 0.0f;
    #pragma unroll
    for (int k = 0; k < KPT; ++k) {
        const float t = (p[k] > pstar) ? p[k] : 1.0f;   // log(1) = 0
        spd += t * (-__logf(t));
    }
    spd = dppSum(spd);

    if (lane == 0) {
        float tie = 0.0f;
        if (haveTie) {
            const float R = (target - mbv) / pstar;     // exclusive-csum rule
            int q = (int)ceilf(R);
            if (q < 1) q = 1;
            if (q > cnt) q = cnt;
            tie = (float)q * pstar * (-__logf(pstar));
        }
        wacc[wid] = (spd + tie) / Z;
    }
    __syncthreads();                     // all waves reach exactly once
    if (tid == 0) {
        atomicAdd(out, wacc[0] + wacc[1] + wacc[2] + wacc[3]);
    }
}

extern "C" void kernel_launch(void* const* d_in, const int* in_sizes, int n_in,
                              void* d_out, int out_size, void* d_ws, size_t ws_size,
                              hipStream_t stream) {
    const float* x = (const float*)d_in[0];   // [B, N, 3]
    const float* y = (const float*)d_in[1];   // [B, M, 3]
    float* out = (float*)d_out;               // scalar

    const int nrows = in_sizes[0] / 3;        // B * N
    const int nblocks = nrows / WPB;

    hipMemsetAsync(out, 0, sizeof(float), stream);   // capture-legal stream op
    apml_row_wave<<<nblocks, WPB * 64, 0, stream>>>(x, y, out);
}

// Round 2
// 175.362 us; speedup vs baseline: 1.1711x; 1.1711x over previous
//
#include <hip/hip_runtime.h>

// APMLSparse: B=4, N=M=4096, D=3.
// loss = sum_rows sum_{kept j} p_ij * d_ij, p = softmax_j(-d_i),
// kept = descending-p prefix until cumulative mass >= P_MIN = 0.8.
//
// R9: R7 structure (proven 130 us) + force p[64] register-resident.
// Post-mortem R8: +ILP/+CAP pushed VGPR 44->68, crossing the 64-VGPR
// occupancy step (45%->30.5%) => regression. Reverted.
// Root cause found in R7 counters: VGPR=44 cannot hold p[64] and there is
// no scratch spill (WRITE_SIZE ~0) => compiler REMATERIALIZES p (reload y
// + sub/fma/sqrt/exp, ~10 VALU + vmcnt wait per element) in EVERY scan,
// compaction, and Phase D. Kernel is VALU-issue-bound on redundant
// recompute (~6-8K VALU instr/wave ~= observed 130 us).
// Fix:
//  - __launch_bounds__(256, 4): VGPR budget 128 (4 waves/SIMD floor, >=
//    the 3.6 currently averaged), removing the compiler's max-occupancy
//    remat incentive.
//  - asm "+v" pin on each p[k] after setup: rematerialization impossible.
//  - pTop = 1.0f (p = exp(-d) < 1 strictly); pmax/dppMax setup dropped.
// Everything else bit-identical to R7 (zl order, scan association, spd
// order, tie logic).

#define MCOLS 4096
#define KPT   64            // 4096 / 64 lanes
#define WPB   4             // waves per block
#define P_MIN 0.8f

// ---- DPP wave64 reductions (old=0 => disabled/out-of-range lanes add 0) ----
template <int CTRL, int RM, int BM, bool BC>
__device__ __forceinline__ float dpp_mov0(float x) {
    return __int_as_float(__builtin_amdgcn_update_dpp(
        0, __float_as_int(x), CTRL, RM, BM, BC));
}
__device__ __forceinline__ float dppSum(float v) {
    v += dpp_mov0<0x111, 0xF, 0xF, true >(v);   // row_shr:1
    v += dpp_mov0<0x112, 0xF, 0xF, true >(v);   // row_shr:2
    v += dpp_mov0<0x114, 0xF, 0xF, true >(v);   // row_shr:4
    v += dpp_mov0<0x118, 0xF, 0xF, true >(v);   // row_shr:8
    v += dpp_mov0<0x142, 0xA, 0xF, false>(v);   // row_bcast15 -> rows 1,3
    v += dpp_mov0<0x143, 0xC, 0xF, false>(v);   // row_bcast31 -> rows 2,3
    return __int_as_float(__builtin_amdgcn_readlane(__float_as_int(v), 63));
}
__device__ __forceinline__ float dppMax(float v) {   // nonneg inputs only
    v = fmaxf(v, dpp_mov0<0x111, 0xF, 0xF, true >(v));
    v = fmaxf(v, dpp_mov0<0x112, 0xF, 0xF, true >(v));
    v = fmaxf(v, dpp_mov0<0x114, 0xF, 0xF, true >(v));
    v = fmaxf(v, dpp_mov0<0x118, 0xF, 0xF, true >(v));
    v = fmaxf(v, dpp_mov0<0x142, 0xA, 0xF, false>(v));
    v = fmaxf(v, dpp_mov0<0x143, 0xC, 0xF, false>(v));
    return __int_as_float(__builtin_amdgcn_readlane(__float_as_int(v), 63));
}

__global__ __launch_bounds__(WPB * 64, 4) void apml_row_wave(
        const float* __restrict__ x, const float* __restrict__ y,
        float* __restrict__ out) {
    __shared__ __align__(16) float scomp[WPB * 256];
    __shared__ float wacc[WPB];

    const int tid  = threadIdx.x;
    const int wid  = tid >> 6;
    const int lane = tid & 63;
    const int row  = blockIdx.x * WPB + wid;
    const int b    = row >> 12;                 // row / 4096

    const float x0 = x[row * 3 + 0];
    const float x1 = x[row * 3 + 1];
    const float x2 = x[row * 3 + 2];
    const float* yb = y + (size_t)b * MCOLS * 3;

    // ---- setup: p = exp(-d), register-resident; Z via DPP ----
    float p[KPT];
    float zl = 0.0f;
    #pragma unroll
    for (int k = 0; k < KPT; ++k) {
        const int j = k * 64 + lane;
        const float y0 = yb[j * 3 + 0];
        const float y1 = yb[j * 3 + 1];
        const float y2 = yb[j * 3 + 2];
        const float dx = x0 - y0, dy = x1 - y1, dz = x2 - y2;
        const float sq = fmaxf(dx * dx + dy * dy + dz * dz, 1e-12f); // EPS^2
        const float pk = __expf(-sqrtf(sq));
        p[k] = pk;
        zl  += pk;
    }
    // Pin p[] into VGPRs: opaque def forbids rematerialization of the
    // load+exp chain at later uses. 64 VGPRs held; budget is 128.
    #pragma unroll
    for (int k = 0; k < KPT; ++k) asm volatile("" : "+v"(p[k]));

    const float Z      = dppSum(zl);
    const float target = P_MIN * Z;
    const float pTop   = 1.0f;   // p = exp(-d), d >= 1e-6 => p < 1 strictly

    // ---- sampled warm-start: 5 probes on p[0..3] (first 256 elements) ----
    float ssl = 0.0f, ssh = pTop;
    {
        float eGl = 16.0f * dppSum(p[0] + p[1] + p[2] + p[3]);  // Ghat(0)
        float eGh = 0.0f;
        for (int it = 0; it < 5; ++it) {
            float s;
            if (it & 1) {
                s = 0.5f * (ssl + ssh);
            } else {
                const float den = fmaxf(eGl - eGh, 1e-30f);
                s = ssl + (ssh - ssl) * ((eGl - target) / den);
            }
            if (!(s > ssl && s < ssh)) s = 0.5f * (ssl + ssh);
            if (!(s > ssl && s < ssh)) break;
            float m = 0.0f;
            #pragma unroll
            for (int q = 0; q < 4; ++q) m += (p[q] >= s) ? p[q] : 0.0f;
            m = 16.0f * dppSum(m);
            if (m >= target) { ssl = s; eGl = m; }
            else             { ssh = s; eGh = m; }
        }
    }

    // ---- Phase A: exact probes (seeded by ssl, ssh) until band <= 256 ----
    // Invariant: G(sl) >= target > G(sh), G(s) = mass of {p >= s}.
    float sl = 0.0f, sh = pTop;
    float Gl = Z,    Gh = 0.0f;
    int   Cl = MCOLS, Ch = 0;

    for (int it = 0; it < 12 && (Cl - Ch) > 256; ++it) {
        float s;
        if      (it == 0) s = ssl;
        else if (it == 1) s = ssh;
        else if (it & 1)  s = 0.5f * (sl + sh);
        else {
            const float den = fmaxf(Gl - Gh, 1e-30f);
            s = sl + (sh - sl) * ((Gl - target) / den);
        }
        if (!(s > sl && s < sh)) s = 0.5f * (sl + sh);
        if (!(s > sl && s < sh)) break;        // ulp-width bracket

        float m = 0.0f;
        int   c = 0;
        #pragma unroll
        for (int k = 0; k < KPT; ++k) {
            const bool ge = (p[k] >= s);
            m += ge ? p[k] : 0.0f;
            c += (int)__popcll(__ballot(ge));
        }
        m = dppSum(m);
        if (m >= target) { sl = s; Gl = m; Cl = c; }
        else             { sh = s; Gh = m; Ch = c; }
    }

    // ---- Phase B: compact band [sl, sh) into 4 regs per lane ----
    int C = 0;
    #pragma unroll
    for (int k = 0; k < KPT; ++k) {
        const bool band = (p[k] >= sl) && (p[k] < sh);
        const unsigned long long mk = __ballot(band);
        if (band) {
            const unsigned mlo = (unsigned)mk, mhi = (unsigned)(mk >> 32);
            const int within = __builtin_amdgcn_mbcnt_hi(
                                   mhi, __builtin_amdgcn_mbcnt_lo(mlo, 0));
            const int pos = C + within;
            if (pos < 256) scomp[wid * 256 + pos] = p[k];
        }
        C += (int)__popcll(mk);
    }
    __builtin_amdgcn_s_waitcnt(0);             // drain ds_writes (same wave)
    float cp[4];
    bool  cv[4];
    #pragma unroll
    for (int q = 0; q < 4; ++q) {
        const int idx = q * 64 + lane;
        cv[q] = (idx < C) && (idx < 256);
        cp[q] = cv[q] ? scomp[wid * 256 + idx] : 0.0f;
    }

    float pstar, mb = 0.0f;
    int   cnt = 1;
    bool  haveTie;

    if (C > 256) {
        // fallback (rare): keep everything >= sl (off by <=2 boundary elems)
        pstar = (sl > 0.0f) ? __uint_as_float(__float_as_uint(sl) - 1u) : 0.0f;
        haveTie = false;
    } else {
        // ---- Phase C1: cheap fine probes on the compact set ----
        float lo_s = sl, hi_s = sh, lo_G = Gl, hi_G = Gh;
        int   lo_C = Cl, hi_C = Ch;
        for (int it = 0; it < 10 && (lo_C - hi_C) > 2; ++it) {
            float s;
            if (it & 1) {
                s = 0.5f * (lo_s + hi_s);
            } else {
                const float den = fmaxf(lo_G - hi_G, 1e-30f);
                s = lo_s + (hi_s - lo_s) * ((lo_G - target) / den);
            }
            if (!(s > lo_s && s < hi_s)) s = 0.5f * (lo_s + hi_s);
            if (!(s > lo_s && s < hi_s)) break;

            float m = 0.0f;
            int   c = Ch;
            #pragma unroll
            for (int q = 0; q < 4; ++q) {
                const bool ge = cv[q] && (cp[q] >= s);
                m += ge ? cp[q] : 0.0f;
                c += (int)__popcll(__ballot(ge));
            }
            m = Gh + dppSum(m);
            if (m >= target) { lo_s = s; lo_G = m; lo_C = c; }
            else             { hi_s = s; hi_G = m; hi_C = c; }
        }

        // ---- Phase C2: exact distinct-value walk downward from hi_s ----
        float scur = hi_s, M = hi_G;
        bool ok = false;
        pstar = lo_s;
        for (int e = 0; e < 16; ++e) {
            float vl = 0.0f;
            #pragma unroll
            for (int q = 0; q < 4; ++q)
                vl = fmaxf(vl, (cv[q] && cp[q] < scur) ? cp[q] : 0.0f);
            const float v = dppMax(vl);
            if (!(v > 0.0f)) break;            // fp knife-edge; fallback
            int cvn = 0;
            #pragma unroll
            for (int q = 0; q < 4; ++q)
                cvn += (int)__popcll(__ballot(cv[q] && (cp[q] == v)));
            const float Mn = M + v * (float)cvn;  // exact: ties bit-identical
            if (Mn >= target) { pstar = v; mb = M; cnt = cvn; ok = true; break; }
            M = Mn; scur = v;
        }
        haveTie = ok;
        if (!ok) {
            pstar = (lo_s > 0.0f) ? __uint_as_float(__float_as_uint(lo_s) - 1u)
                                  : 0.0f;
        }
    }

    // ---- Phase D: spd = sum_{p > p*} p * (-log p) via select-to-1 ----
    float spd = 0.0f;
    #pragma unroll
    for (int k = 0; k < KPT; ++k) {
        const float t = (p[k] > pstar) ? p[k] : 1.0f;   // log(1) = 0
        spd += t * (-__logf(t));
    }
    spd = dppSum(spd);

    if (lane == 0) {
        float tie = 0.0f;
        if (haveTie) {
            const float R = (target - mb) / pstar;      // exclusive-csum rule
            int q = (int)ceilf(R);
            if (q < 1) q = 1;
            if (q > cnt) q = cnt;
            tie = (float)q * pstar * (-__logf(pstar));
        }
        wacc[wid] = (spd + tie) / Z;
    }
    __syncthreads();                     // all waves reach exactly once
    if (tid == 0) {
        atomicAdd(out, wacc[0] + wacc[1] + wacc[2] + wacc[3]);
    }
}

extern "C" void kernel_launch(void* const* d_in, const int* in_sizes, int n_in,
                              void* d_out, int out_size, void* d_ws, size_t ws_size,
                              hipStream_t stream) {
    const float* x = (const float*)d_in[0];   // [B, N, 3]
    const float* y = (const float*)d_in[1];   // [B, M, 3]
    float* out = (float*)d_out;               // scalar

    const int nrows = in_sizes[0] / 3;        // B * N
    const int nblocks = nrows / WPB;

    hipMemsetAsync(out, 0, sizeof(float), stream);   // capture-legal stream op
    apml_row_wave<<<nblocks, WPB * 64, 0, stream>>>(x, y, out);
}

// Round 3
// 166.131 us; speedup vs baseline: 1.2362x; 1.0556x over previous
//
#include <hip/hip_runtime.h>

// APMLSparse: B=4, N=M=4096, D=3.
// loss = sum_rows sum_{kept j} p_ij * d_ij, p = softmax_j(-d_i),
// kept = descending-p prefix until cumulative mass >= P_MIN = 0.8.
//
// R10: back to the proven R7 structure (130 us dispatch) + three cuts.
// Post-mortems:
//  R8: extra ILP/CAP crossed 64-VGPR step (occ 45->30) => slower.
//  R9: VALUBusy*dur identical to R7 => NO remat ever existed; pin only
//      squeezed temps into a 64-reg bucket (stalls, VALU 106->80). The
//      kernel is LATENCY-bound: serial 64-deep ordered add chains per
//      probe (~256 cyc), ~7 sequential probe rounds, and a 4096-way
//      same-address atomicAdd tail.
// Changes vs R7 (regalloc regime preserved: no launch-bounds floor, no pins):
//  1. Full-set probe scans use 4 independent accumulator chains (+3 VGPR),
//     cutting probe critical path 256 -> ~90 cyc. pml max-chain 4-way too
//     (max is order-insensitive: exact). zl and spd chains UNCHANGED
//     (value-critical order).
//  2. First Phase-A probe evaluates ssl AND ssh in one pass (2 chains),
//     saving one full 64-element scan.
//  3. Final reduction: block partial sums to d_ws + tiny deterministic
//     reduce kernel; removes 4096 serialized same-address atomics.
//     (Current atomic order is already nondeterministic and passes, so
//     reassociation is safe; atomic path kept as ws_size fallback.)

#define MCOLS 4096
#define KPT   64            // 4096 / 64 lanes
#define WPB   4             // waves per block
#define P_MIN 0.8f

// ---- DPP wave64 reductions (old=0 => disabled/out-of-range lanes add 0) ----
template <int CTRL, int RM, int BM, bool BC>
__device__ __forceinline__ float dpp_mov0(float x) {
    return __int_as_float(__builtin_amdgcn_update_dpp(
        0, __float_as_int(x), CTRL, RM, BM, BC));
}
__device__ __forceinline__ float dppSum(float v) {
    v += dpp_mov0<0x111, 0xF, 0xF, true >(v);   // row_shr:1
    v += dpp_mov0<0x112, 0xF, 0xF, true >(v);   // row_shr:2
    v += dpp_mov0<0x114, 0xF, 0xF, true >(v);   // row_shr:4
    v += dpp_mov0<0x118, 0xF, 0xF, true >(v);   // row_shr:8
    v += dpp_mov0<0x142, 0xA, 0xF, false>(v);   // row_bcast15 -> rows 1,3
    v += dpp_mov0<0x143, 0xC, 0xF, false>(v);   // row_bcast31 -> rows 2,3
    return __int_as_float(__builtin_amdgcn_readlane(__float_as_int(v), 63));
}
__device__ __forceinline__ void dppSum2(float& a, float& b) {
    a += dpp_mov0<0x111, 0xF, 0xF, true >(a); b += dpp_mov0<0x111, 0xF, 0xF, true >(b);
    a += dpp_mov0<0x112, 0xF, 0xF, true >(a); b += dpp_mov0<0x112, 0xF, 0xF, true >(b);
    a += dpp_mov0<0x114, 0xF, 0xF, true >(a); b += dpp_mov0<0x114, 0xF, 0xF, true >(b);
    a += dpp_mov0<0x118, 0xF, 0xF, true >(a); b += dpp_mov0<0x118, 0xF, 0xF, true >(b);
    a += dpp_mov0<0x142, 0xA, 0xF, false>(a); b += dpp_mov0<0x142, 0xA, 0xF, false>(b);
    a += dpp_mov0<0x143, 0xC, 0xF, false>(a); b += dpp_mov0<0x143, 0xC, 0xF, false>(b);
    a = __int_as_float(__builtin_amdgcn_readlane(__float_as_int(a), 63));
    b = __int_as_float(__builtin_amdgcn_readlane(__float_as_int(b), 63));
}
__device__ __forceinline__ float dppMax(float v) {   // nonneg inputs only
    v = fmaxf(v, dpp_mov0<0x111, 0xF, 0xF, true >(v));
    v = fmaxf(v, dpp_mov0<0x112, 0xF, 0xF, true >(v));
    v = fmaxf(v, dpp_mov0<0x114, 0xF, 0xF, true >(v));
    v = fmaxf(v, dpp_mov0<0x118, 0xF, 0xF, true >(v));
    v = fmaxf(v, dpp_mov0<0x142, 0xA, 0xF, false>(v));
    v = fmaxf(v, dpp_mov0<0x143, 0xC, 0xF, false>(v));
    return __int_as_float(__builtin_amdgcn_readlane(__float_as_int(v), 63));
}

__global__ __launch_bounds__(WPB * 64) void apml_row_wave(
        const float* __restrict__ x, const float* __restrict__ y,
        float* __restrict__ partial, float* __restrict__ out) {
    __shared__ __align__(16) float scomp[WPB * 256];
    __shared__ float wacc[WPB];

    const int tid  = threadIdx.x;
    const int wid  = tid >> 6;
    const int lane = tid & 63;
    const int row  = blockIdx.x * WPB + wid;
    const int b    = row >> 12;                 // row / 4096

    const float x0 = x[row * 3 + 0];
    const float x1 = x[row * 3 + 1];
    const float x2 = x[row * 3 + 2];
    const float* yb = y + (size_t)b * MCOLS * 3;

    // ---- setup: p = exp(-d), register-resident; Z and pmax via DPP ----
    // zl chain order is value-critical (Z) -> serial, unchanged from R7.
    // pml (max) is order-insensitive -> 4 chains, exact same result.
    float p[KPT];
    float zl = 0.0f;
    float pm0 = 0.0f, pm1 = 0.0f, pm2 = 0.0f, pm3 = 0.0f;
    #pragma unroll
    for (int k = 0; k < KPT; ++k) {
        const int j = k * 64 + lane;
        const float y0 = yb[j * 3 + 0];
        const float y1 = yb[j * 3 + 1];
        const float y2 = yb[j * 3 + 2];
        const float dx = x0 - y0, dy = x1 - y1, dz = x2 - y2;
        const float sq = fmaxf(dx * dx + dy * dy + dz * dz, 1e-12f); // EPS^2
        const float pk = __expf(-sqrtf(sq));
        p[k] = pk;
        zl  += pk;
        if      ((k & 3) == 0) pm0 = fmaxf(pm0, pk);
        else if ((k & 3) == 1) pm1 = fmaxf(pm1, pk);
        else if ((k & 3) == 2) pm2 = fmaxf(pm2, pk);
        else                   pm3 = fmaxf(pm3, pk);
    }
    const float Z    = dppSum(zl);
    const float pmax = dppMax(fmaxf(fmaxf(pm0, pm1), fmaxf(pm2, pm3)));
    const float target = P_MIN * Z;
    const float pTop = __uint_as_float(__float_as_uint(pmax) + 1u);

    // ---- sampled warm-start: 5 probes on p[0..3] (first 256 elements) ----
    float ssl = 0.0f, ssh = pTop;
    {
        float eGl = 16.0f * dppSum(p[0] + p[1] + p[2] + p[3]);  // Ghat(0)
        float eGh = 0.0f;
        for (int it = 0; it < 5; ++it) {
            float s;
            if (it & 1) {
                s = 0.5f * (ssl + ssh);
            } else {
                const float den = fmaxf(eGl - eGh, 1e-30f);
                s = ssl + (ssh - ssl) * ((eGl - target) / den);
            }
            if (!(s > ssl && s < ssh)) s = 0.5f * (ssl + ssh);
            if (!(s > ssl && s < ssh)) break;
            float m = 0.0f;
            #pragma unroll
            for (int q = 0; q < 4; ++q) m += (p[q] >= s) ? p[q] : 0.0f;
            m = 16.0f * dppSum(m);
            if (m >= target) { ssl = s; eGl = m; }
            else             { ssh = s; eGh = m; }
        }
    }

    // ---- Phase A0: dual-threshold pass, evaluates ssl AND ssh at once ----
    // Invariant from here: G(sl) >= target > G(sh), G(s) = mass of {p >= s}.
    float sl = 0.0f, sh = pTop;
    float Gl = Z,    Gh = 0.0f;
    int   Cl = MCOLS, Ch = 0;
    {
        float ml = 0.0f, mh = 0.0f;
        int   cl_ = 0,   ch_ = 0;
        #pragma unroll
        for (int k = 0; k < KPT; ++k) {
            const float pk = p[k];
            const bool gl = (pk >= ssl);
            const bool gh = (pk >= ssh);
            ml += gl ? pk : 0.0f; cl_ += (int)__popcll(__ballot(gl));
            mh += gh ? pk : 0.0f; ch_ += (int)__popcll(__ballot(gh));
        }
        dppSum2(ml, mh);
        if (ml >= target) { sl = ssl; Gl = ml; Cl = cl_; }
        else              { sh = ssl; Gh = ml; Ch = cl_; }
        if (mh >= target) { sl = ssh; Gl = mh; Cl = ch_; }
        else if (ssh < sh){ sh = ssh; Gh = mh; Ch = ch_; }
    }

    // ---- Phase A: exact probes until band <= 256 (4-chain scans) ----
    for (int it = 0; it < 10 && (Cl - Ch) > 256; ++it) {
        float s;
        if (it & 1) {
            s = 0.5f * (sl + sh);
        } else {
            const float den = fmaxf(Gl - Gh, 1e-30f);
            s = sl + (sh - sl) * ((Gl - target) / den);
        }
        if (!(s > sl && s < sh)) s = 0.5f * (sl + sh);
        if (!(s > sl && s < sh)) break;        // ulp-width bracket

        float m0 = 0.0f, m1 = 0.0f, m2 = 0.0f, m3 = 0.0f;
        int   c = 0;
        #pragma unroll
        for (int k = 0; k < KPT; k += 4) {
            const bool g0 = (p[k]     >= s);
            const bool g1 = (p[k + 1] >= s);
            const bool g2 = (p[k + 2] >= s);
            const bool g3 = (p[k + 3] >= s);
            m0 += g0 ? p[k]     : 0.0f; c += (int)__popcll(__ballot(g0));
            m1 += g1 ? p[k + 1] : 0.0f; c += (int)__popcll(__ballot(g1));
            m2 += g2 ? p[k + 2] : 0.0f; c += (int)__popcll(__ballot(g2));
            m3 += g3 ? p[k + 3] : 0.0f; c += (int)__popcll(__ballot(g3));
        }
        const float m = dppSum((m0 + m1) + (m2 + m3));
        if (m >= target) { sl = s; Gl = m; Cl = c; }
        else             { sh = s; Gh = m; Ch = c; }
    }

    // ---- Phase B: compact band [sl, sh) into 4 regs per lane ----
    int C = 0;
    #pragma unroll
    for (int k = 0; k < KPT; ++k) {
        const bool band = (p[k] >= sl) && (p[k] < sh);
        const unsigned long long mk = __ballot(band);
        if (band) {
            const unsigned mlo = (unsigned)mk, mhi = (unsigned)(mk >> 32);
            const int within = __builtin_amdgcn_mbcnt_hi(
                                   mhi, __builtin_amdgcn_mbcnt_lo(mlo, 0));
            const int pos = C + within;
            if (pos < 256) scomp[wid * 256 + pos] = p[k];
        }
        C += (int)__popcll(mk);
    }
    __builtin_amdgcn_s_waitcnt(0);             // drain ds_writes (same wave)
    float cp[4];
    bool  cv[4];
    #pragma unroll
    for (int q = 0; q < 4; ++q) {
        const int idx = q * 64 + lane;
        cv[q] = (idx < C) && (idx < 256);
        cp[q] = cv[q] ? scomp[wid * 256 + idx] : 0.0f;
    }

    float pstar, mb = 0.0f;
    int   cnt = 1;
    bool  haveTie;

    if (C > 256) {
        // fallback (rare): keep everything >= sl (off by <=2 boundary elems)
        pstar = (sl > 0.0f) ? __uint_as_float(__float_as_uint(sl) - 1u) : 0.0f;
        haveTie = false;
    } else {
        // ---- Phase C1: cheap fine probes on the compact set ----
        float lo_s = sl, hi_s = sh, lo_G = Gl, hi_G = Gh;
        int   lo_C = Cl, hi_C = Ch;
        for (int it = 0; it < 10 && (lo_C - hi_C) > 2; ++it) {
            float s;
            if (it & 1) {
                s = 0.5f * (lo_s + hi_s);
            } else {
                const float den = fmaxf(lo_G - hi_G, 1e-30f);
                s = lo_s + (hi_s - lo_s) * ((lo_G - target) / den);
            }
            if (!(s > lo_s && s < hi_s)) s = 0.5f * (lo_s + hi_s);
            if (!(s > lo_s && s < hi_s)) break;

            float m = 0.0f;
            int   c = Ch;
            #pragma unroll
            for (int q = 0; q < 4; ++q) {
                const bool ge = cv[q] && (cp[q] >= s);
                m += ge ? cp[q] : 0.0f;
                c += (int)__popcll(__ballot(ge));
            }
            m = Gh + dppSum(m);
            if (m >= target) { lo_s = s; lo_G = m; lo_C = c; }
            else             { hi_s = s; hi_G = m; hi_C = c; }
        }

        // ---- Phase C2: exact distinct-value walk downward from hi_s ----
        float scur = hi_s, M = hi_G;
        bool ok = false;
        pstar = lo_s;
        for (int e = 0; e < 16; ++e) {
            float vl = 0.0f;
            #pragma unroll
            for (int q = 0; q < 4; ++q)
                vl = fmaxf(vl, (cv[q] && cp[q] < scur) ? cp[q] : 0.0f);
            const float v = dppMax(vl);
            if (!(v > 0.0f)) break;            // fp knife-edge; fallback
            int cvn = 0;
            #pragma unroll
            for (int q = 0; q < 4; ++q)
                cvn += (int)__popcll(__ballot(cv[q] && (cp[q] == v)));
            const float Mn = M + v * (float)cvn;  // exact: ties bit-identical
            if (Mn >= target) { pstar = v; mb = M; cnt = cvn; ok = true; break; }
            M = Mn; scur = v;
        }
        haveTie = ok;
        if (!ok) {
            pstar = (lo_s > 0.0f) ? __uint_as_float(__float_as_uint(lo_s) - 1u)
                                  : 0.0f;
        }
    }

    // ---- Phase D: spd = sum_{p > p*} p * (-log p) via select-to-1 ----
    // (order value-critical: unchanged from R7)
    float spd = 0.0f;
    #pragma unroll
    for (int k = 0; k < KPT; ++k) {
        const float t = (p[k] > pstar) ? p[k] : 1.0f;   // log(1) = 0
        spd += t * (-__logf(t));
    }
    spd = dppSum(spd);

    if (lane == 0) {
        float tie = 0.0f;
        if (haveTie) {
            const float R = (target - mb) / pstar;      // exclusive-csum rule
            int q = (int)ceilf(R);
            if (q < 1) q = 1;
            if (q > cnt) q = cnt;
            tie = (float)q * pstar * (-__logf(pstar));
        }
        wacc[wid] = (spd + tie) / Z;
    }
    __syncthreads();                     // all waves reach exactly once
    if (tid == 0) {
        const float v = wacc[0] + wacc[1] + wacc[2] + wacc[3];
        if (partial) partial[blockIdx.x] = v;   // no same-address atomic
        else         atomicAdd(out, v);         // ws_size fallback
    }
}

// Deterministic 2nd-stage reduce: nblocks (<=4096) floats -> out[0].
__global__ __launch_bounds__(1024) void apml_reduce(
        const float* __restrict__ partial, float* __restrict__ out, int n) {
    __shared__ float s[16];
    const int t = threadIdx.x;
    float a = 0.0f;
    #pragma unroll
    for (int q = 0; q < 4; ++q) {
        const int i = t * 4 + q;
        a += (i < n) ? partial[i] : 0.0f;
    }
    a = dppSum(a);
    if ((t & 63) == 0) s[t >> 6] = a;
    __syncthreads();
    if (t == 0) {
        float r = 0.0f;
        #pragma unroll
        for (int w = 0; w < 16; ++w) r += s[w];
        out[0] = r;
    }
}

extern "C" void kernel_launch(void* const* d_in, const int* in_sizes, int n_in,
                              void* d_out, int out_size, void* d_ws, size_t ws_size,
                              hipStream_t stream) {
    const float* x = (const float*)d_in[0];   // [B, N, 3]
    const float* y = (const float*)d_in[1];   // [B, M, 3]
    float* out = (float*)d_out;               // scalar

    const int nrows = in_sizes[0] / 3;        // B * N
    const int nblocks = nrows / WPB;          // 4096

    if (d_ws && ws_size >= (size_t)nblocks * sizeof(float) && nblocks <= 4096) {
        float* partial = (float*)d_ws;
        apml_row_wave<<<nblocks, WPB * 64, 0, stream>>>(x, y, partial, out);
        apml_reduce<<<1, 1024, 0, stream>>>(partial, out, nblocks);
    } else {
        hipMemsetAsync(out, 0, sizeof(float), stream);   // capture-legal
        apml_row_wave<<<nblocks, WPB * 64, 0, stream>>>(x, y, nullptr, out);
    }
}